// Round 11
// baseline (116.562 us; speedup 1.0000x reference)
//
#include <hip/hip_runtime.h>
#include <math.h>

#define HH 256
#define WW 256
#define NTHREADS 256
#define CHUNKG 256            // gaussians per block-slice (before culling)
#define HWPIX (HH * WW)
#define PADIDX(i) ((i) + ((i) >> 3))   // quadrant reads hit distinct banks
#define ECUT (-15.0f)                  // drop gaussians whose ROW-PEAK log2(alpha) < ECUT
#define CNT_OFF_FLOATS 1024            // 4KB reserved for per-row tickets at ws start

typedef short s8v __attribute__((ext_vector_type(8)));   // 8 bf16 (4 VGPRs)
typedef float f4v __attribute__((ext_vector_type(4)));   // MFMA accumulator

__device__ __forceinline__ unsigned pk_trunc(float lo, float hi) {
    return (__float_as_uint(hi) & 0xFFFF0000u) | (__float_as_uint(lo) >> 16);
}
__device__ __forceinline__ float fexp2(float x) {
    return __builtin_amdgcn_exp2f(x);   // raw v_exp_f32; -inf -> 0
}

// ---------------------------------------------------------------------------
// Fused partial+finish kernel. Block = one image row (y=blockIdx.x) x one
// slice of 256 gaussians (blockIdx.y; nslice = ceil(N/256)). 4 waves.
// Cull on true row-peak: rowpeak = coef*(y-v)^2 + log2(op); survivors
// compacted via 4-wave ballot, padded to x32 with E=-inf dummies.
//   log2(alpha) = A*x^2 + B*x + E,  E = (A*y + C)*y + D
// GEMM via mfma_f32_16x16x32_bf16 (A=alpha 16px x 32g, B=payload {1,r,g,b,z}).
// After storing partials: threadfence + per-row atomic ticket; the last
// slice-block for this row reduces nslice x 5 planes (L2-hot) and writes out.
// ---------------------------------------------------------------------------
__global__ __launch_bounds__(NTHREADS, 4) void render_kernel(
    const float* __restrict__ means,
    const float* __restrict__ colors,
    const float* __restrict__ opacity,
    const float* __restrict__ scales,
    const float* __restrict__ K,
    const float* __restrict__ M,
    float* __restrict__ ws,        // [tickets(1024 f)][partials nslice*5*HWPIX]
    float* __restrict__ out,
    int N, int nslice)
{
    __shared__ float4   prm[PADIDX(CHUNKG - 1) + 1];   // {A, B, E, 0}
    __shared__ float4   colf[CHUNKG];                  // {r, g, b, z}
    __shared__ unsigned bfr[(CHUNKG / 32) * 256];      // B-frags
    __shared__ int      scnt[4];
    __shared__ int      ticket;

    float* partials = ws + CNT_OFF_FLOATS;
    int*   tickets  = (int*)ws;

    const int tid = threadIdx.x;
    const int y   = blockIdx.x;
    const int g0  = blockIdx.y * CHUNKG;
    const float yf = (float)y;

    // ---- Phase 1a: project + cull flag (all 256 threads) ----
    float A = 0.f, Bc = 0.f, E = -INFINITY;
    float4 cf = make_float4(0.f, 0.f, 0.f, 0.f);
    float rowpeak = -INFINITY;
    {
        const int n = g0 + tid;
        if (n < N) {
            const float wx = means[3 * n + 0];
            const float wy = means[3 * n + 1];
            const float wz = means[3 * n + 2];
            const float px = M[0] * wx + M[1] * wy + M[2]  * wz + M[3];
            const float py = M[4] * wx + M[5] * wy + M[6]  * wz + M[7];
            const float pz = M[8] * wx + M[9] * wy + M[10] * wz + M[11];
            const float rz = 1.0f / pz;
            const float u  = (K[0] * px + K[1] * py + K[2] * pz) * rz;
            const float v  = (K[4] * py + K[5] * pz) * rz;
            const bool valid = (pz > 1e-4f)
                            && (u >= -(float)WW) && (u <= 2.0f * (float)WW)
                            && (v >= -(float)HH) && (v <= 2.0f * (float)HH);
            if (valid) {
                const float op  = opacity[n];
                const float sig = fmaxf(scales[n] * 256.0f, 1.0f);
                const float coef = -0.72134752044448170368f / (sig * sig);
                const float lop = __log2f(op);                  // op=0 -> -inf
                const float dyv = yf - v;
                rowpeak = fmaf(coef, dyv * dyv, lop);
                A  = coef;
                Bc = -2.0f * coef * u;
                const float C = -2.0f * coef * v;
                const float D = fmaf(coef, fmaf(u, u, v * v), lop);
                E  = fmaf(fmaf(A, yf, C), yf, D);
                cf = make_float4(colors[3 * n + 0], colors[3 * n + 1],
                                 colors[3 * n + 2], pz);
            }
        }
    }
    const bool keep = (rowpeak > ECUT);
    const unsigned long long mask = __ballot(keep);
    const int lane = tid & 63;
    const int wv   = tid >> 6;
    const int prefix = __popcll(mask & ((1ull << lane) - 1ull));
    if (lane == 0) scnt[wv] = __popcll(mask);
    __syncthreads();

    int basepos = 0;
    #pragma unroll
    for (int w = 0; w < 4; ++w) if (w < wv) basepos += scnt[w];
    const int cnt    = scnt[0] + scnt[1] + scnt[2] + scnt[3];
    const int padded = (cnt + 31) & ~31;
    const int nch    = padded >> 5;

    // ---- Phase 1b: compacted writes + pad dummies ----
    if (keep) {
        const int pos = basepos + prefix;
        prm[PADIDX(pos)] = make_float4(A, Bc, E, 0.f);
        colf[pos] = cf;
    }
    if (tid < padded - cnt) {
        const int pos = cnt + tid;
        prm[PADIDX(pos)] = make_float4(0.f, 0.f, -INFINITY, 0.f);
        colf[pos] = make_float4(0.f, 0.f, 0.f, 0.f);
    }
    __syncthreads();

    // ---- Phase 2: build B-fragments ----
    for (int e = tid; e < nch * 256; e += NTHREADS) {
        const int lane6 = (e >> 2) & 63;
        const int reg   = e & 3;
        const int kl    = ((e >> 8) << 5) + ((lane6 >> 4) << 3) + (reg << 1);
        const int col   = lane6 & 15;
        const float4 c0 = colf[kl];
        const float4 c1 = colf[kl + 1];
        const float lo = (col == 0) ? 1.f : (col == 1) ? c0.x : (col == 2) ? c0.y
                       : (col == 3) ? c0.z : (col == 4) ? c0.w : 0.f;
        const float hi = (col == 0) ? 1.f : (col == 1) ? c1.x : (col == 2) ? c1.y
                       : (col == 3) ? c1.z : (col == 4) ? c1.w : 0.f;
        bfr[e] = pk_trunc(lo, hi);
    }
    __syncthreads();

    // ---- Phase 3: alpha eval + MFMA accumulate ----
    const int kq = (lane >> 4) << 3;

    f4v acc[4];
    #pragma unroll
    for (int t = 0; t < 4; ++t) acc[t] = (f4v){0.f, 0.f, 0.f, 0.f};

    float xs[4], xxs[4];
    #pragma unroll
    for (int t = 0; t < 4; ++t) {
        xs[t]  = (float)(wv * 64 + t * 16 + (lane & 15));
        xxs[t] = xs[t] * xs[t];
    }

    for (int c = 0; c < nch; ++c) {
        float4 P[8];
        #pragma unroll
        for (int j = 0; j < 8; ++j) P[j] = prm[PADIDX(c * 32 + kq) + j];

        union { s8v v; uint4 q; } Bf;
        Bf.q = *(const uint4*)&bfr[c * 256 + lane * 4];

        #pragma unroll
        for (int t = 0; t < 4; ++t) {
            union { s8v v; unsigned u[4]; } Af;
            #pragma unroll
            for (int r = 0; r < 4; ++r) {
                const float4 p0 = P[2 * r];
                const float4 p1 = P[2 * r + 1];
                const float a0 = fminf(fexp2(fmaf(p0.y, xs[t], fmaf(p0.x, xxs[t], p0.z))), 0.95f);
                const float a1 = fminf(fexp2(fmaf(p1.y, xs[t], fmaf(p1.x, xxs[t], p1.z))), 0.95f);
                Af.u[r] = pk_trunc(a0, a1);
            }
            acc[t] = __builtin_amdgcn_mfma_f32_16x16x32_bf16(Af.v, Bf.v, acc[t], 0, 0, 0);
        }
    }

    // ---- Store partials: lane holds payload col=lane&15, rows (lane>>4)*4+r
    const int col = lane & 15;
    if (col < 5) {
        float* pl = partials + ((size_t)blockIdx.y * 5 + col) * HWPIX + (size_t)y * WW;
        const int rb = (lane >> 4) << 2;
        #pragma unroll
        for (int t = 0; t < 4; ++t) {
            #pragma unroll
            for (int r = 0; r < 4; ++r) {
                pl[wv * 64 + t * 16 + rb + r] = acc[t][r];
            }
        }
    }

    // ---- Ticket: last slice-block for this row finishes it ----
    __threadfence();
    __syncthreads();
    if (tid == 0) ticket = atomicAdd(&tickets[y], 1);
    __syncthreads();
    if (ticket == nslice - 1) {
        __threadfence();
        float s = 0.f, ar = 0.f, ag = 0.f, ab = 0.f, az = 0.f;
        for (int sl = 0; sl < nslice; ++sl) {
            const float* q = partials + (size_t)(sl * 5) * HWPIX + (size_t)y * WW + tid;
            s  += q[0 * HWPIX];
            ar += q[1 * HWPIX];
            ag += q[2 * HWPIX];
            ab += q[3 * HWPIX];
            az += q[4 * HWPIX];
        }
        const float inv   = 1.0f / (s + 1e-6f);
        const float accum = fminf(s, 1.0f);
        const float bg    = 1.0f - accum;
        float* o = out + (size_t)y * WW + tid;
        o[0 * HWPIX] = fminf(fmaxf(fmaf(ar * inv, accum, bg), 0.0f), 1.0f);
        o[1 * HWPIX] = fminf(fmaxf(fmaf(ag * inv, accum, bg), 0.0f), 1.0f);
        o[2 * HWPIX] = fminf(fmaxf(fmaf(ab * inv, accum, bg), 0.0f), 1.0f);
        o[3 * HWPIX] = accum;
        o[4 * HWPIX] = az * inv;
    }
}

// ---------------------------------------------------------------------------
// Fallback fused kernel (only if ws is too small) — known-good single-pass.
// ---------------------------------------------------------------------------
__global__ __launch_bounds__(NTHREADS) void fused_kernel(
    const float* __restrict__ means,
    const float* __restrict__ colors,
    const float* __restrict__ opacity,
    const float* __restrict__ scales,
    const float* __restrict__ K,
    const float* __restrict__ M,
    float* __restrict__ out,
    int N)
{
    __shared__ float4 sg[256 * 2];
    const int tid = threadIdx.x;
    const int p   = blockIdx.x * NTHREADS + tid;
    const float x = (float)(p & (WW - 1));
    const float y = (float)(p >> 8);
    const float fx = K[0], sk = K[1], cx = K[2], fy = K[4], cy = K[5];

    float s = 0.f, ar = 0.f, ag = 0.f, ab = 0.f, az = 0.f;
    for (int base = 0; base < N; base += 256) {
        const int cnt = min(256, N - base);
        __syncthreads();
        for (int i = tid; i < cnt; i += NTHREADS) {
            const int n = base + i;
            const float wx = means[3 * n + 0];
            const float wy = means[3 * n + 1];
            const float wz = means[3 * n + 2];
            const float px = M[0] * wx + M[1] * wy + M[2]  * wz + M[3];
            const float py = M[4] * wx + M[5] * wy + M[6]  * wz + M[7];
            const float pz = M[8] * wx + M[9] * wy + M[10] * wz + M[11];
            const float rz = 1.0f / pz;
            float u = (fx * px + sk * py + cx * pz) * rz;
            float v = (fy * py + cy * pz) * rz;
            const bool valid = (pz > 1e-4f)
                            && (u >= -(float)WW) && (u <= 2.0f * (float)WW)
                            && (v >= -(float)HH) && (v <= 2.0f * (float)HH);
            const float op = valid ? opacity[n] : 0.0f;
            const float sig = fmaxf(scales[n] * 256.0f, 1.0f);
            float coef = -0.72134752044448170368f / (sig * sig);
            const float lop = __log2f(op);
            float uu = valid ? u : 0.f, vv = valid ? v : 0.f;
            float cfv = valid ? coef : 0.f;
            sg[2 * i + 0] = make_float4(uu, vv, cfv, lop);
            sg[2 * i + 1] = make_float4(colors[3 * n + 0], colors[3 * n + 1],
                                        colors[3 * n + 2], pz);
        }
        __syncthreads();
        for (int n = 0; n < cnt; ++n) {
            const float4 a = sg[2 * n + 0];
            const float4 c = sg[2 * n + 1];
            const float dx = x - a.x, dy = y - a.y;
            const float r2 = fmaf(dy, dy, dx * dx);
            const float alpha = fminf(fexp2(fmaf(r2, a.z, a.w)), 0.95f);
            s += alpha;
            ar = fmaf(alpha, c.x, ar); ag = fmaf(alpha, c.y, ag);
            ab = fmaf(alpha, c.z, ab); az = fmaf(alpha, c.w, az);
        }
    }
    const float inv   = 1.0f / (s + 1e-6f);
    const float accum = fminf(s, 1.0f);
    const float bg    = 1.0f - accum;
    out[0 * HWPIX + p] = fminf(fmaxf(fmaf(ar * inv, accum, bg), 0.0f), 1.0f);
    out[1 * HWPIX + p] = fminf(fmaxf(fmaf(ag * inv, accum, bg), 0.0f), 1.0f);
    out[2 * HWPIX + p] = fminf(fmaxf(fmaf(ab * inv, accum, bg), 0.0f), 1.0f);
    out[3 * HWPIX + p] = accum;
    out[4 * HWPIX + p] = az * inv;
}

extern "C" void kernel_launch(void* const* d_in, const int* in_sizes, int n_in,
                              void* d_out, int out_size, void* d_ws, size_t ws_size,
                              hipStream_t stream) {
    const float* means      = (const float*)d_in[0];
    const float* colors     = (const float*)d_in[1];
    const float* opacity    = (const float*)d_in[2];
    const float* scales     = (const float*)d_in[3];
    const float* intrinsics = (const float*)d_in[4];
    const float* w2c        = (const float*)d_in[5];
    float* out = (float*)d_out;
    float* ws  = (float*)d_ws;

    const int N = in_sizes[0] / 3;
    const int nslice = (N + CHUNKG - 1) / CHUNKG;   // 4 for N=1024

    const size_t need = (size_t)(CNT_OFF_FLOATS + (size_t)nslice * 5 * HWPIX) * 4;
    if (need > ws_size) {
        fused_kernel<<<HWPIX / NTHREADS, NTHREADS, 0, stream>>>(
            means, colors, opacity, scales, intrinsics, w2c, out, N);
        return;
    }

    // zero per-row tickets (graph-capture-safe async memset, deterministic)
    hipMemsetAsync(ws, 0, HH * sizeof(int), stream);

    dim3 grid(HH, nslice);   // 256 rows x 4 slices = 1024 blocks -> 4/CU
    render_kernel<<<grid, NTHREADS, 0, stream>>>(
        means, colors, opacity, scales, intrinsics, w2c, ws, out, N, nslice);
}

// Round 12
// 19.389 us; speedup vs baseline: 6.0119x; 6.0119x over previous
//
#include <hip/hip_runtime.h>
#include <math.h>

#define HH 256
#define WW 256
#define NTHREADS 256
#define CHUNKG 256            // gaussians projected per staging pass
#define HWPIX (HH * WW)
#define PADIDX(i) ((i) + ((i) >> 3))   // quadrant reads hit distinct banks
#define ECUT (-15.0f)                  // drop gaussians whose ROW-PEAK log2(alpha) < ECUT

typedef short s8v __attribute__((ext_vector_type(8)));   // 8 bf16 (4 VGPRs)
typedef float f4v __attribute__((ext_vector_type(4)));   // MFMA accumulator

__device__ __forceinline__ unsigned pk_trunc(float lo, float hi) {
    return (__float_as_uint(hi) & 0xFFFF0000u) | (__float_as_uint(lo) >> 16);
}
__device__ __forceinline__ float fexp2(float x) {
    return __builtin_amdgcn_exp2f(x);   // raw v_exp_f32; -inf -> 0
}

// ---------------------------------------------------------------------------
// Single-kernel renderer. Block = one image row (y = blockIdx.x), grid = 256.
// Loops over ALL gaussians in CHUNKG staging passes:
//   project (256 thr) -> row-peak cull + ballot compact -> pad to x32
//   -> B-frags -> MFMA accumulate (persistent acc across passes).
// Cull predicate (R10-proven): rowpeak = coef*(y-v)^2 + log2(op) > ECUT.
//   log2(alpha) = A*x^2 + B*x + E,  E = (A*y + C)*y + D
// GEMM via mfma_f32_16x16x32_bf16 (A=alpha 16px x 32g, B=payload {1,r,g,b,z});
// both A and B use k=(lane>>4)*8+j enumeration; D: col=lane&15,
// row=(lane>>4)*4+reg. Epilogue: transpose acc through LDS (5x256), then each
// thread normalizes its pixel and writes 5 planes. No workspace, no fences.
// ---------------------------------------------------------------------------
__global__ __launch_bounds__(NTHREADS) void render_kernel(
    const float* __restrict__ means,
    const float* __restrict__ colors,
    const float* __restrict__ opacity,
    const float* __restrict__ scales,
    const float* __restrict__ K,
    const float* __restrict__ M,
    float* __restrict__ out,
    int N)
{
    __shared__ float4   prm[PADIDX(CHUNKG - 1) + 1];   // {A, B, E, 0}
    __shared__ float4   colf[CHUNKG];                  // {r, g, b, z}
    __shared__ unsigned bfr[(CHUNKG / 32) * 256];      // B-frags (8KB max)
    __shared__ int      scnt[4];
    __shared__ float    esum[5 * 256];                 // epilogue transpose

    const int tid  = threadIdx.x;
    const int lane = tid & 63;
    const int wv   = tid >> 6;
    const int y    = blockIdx.x;
    const float yf = (float)y;
    const int kq   = (lane >> 4) << 3;   // lane's k-block base (0,8,16,24)

    f4v acc[4];
    #pragma unroll
    for (int t = 0; t < 4; ++t) acc[t] = (f4v){0.f, 0.f, 0.f, 0.f};

    float xs[4], xxs[4];
    #pragma unroll
    for (int t = 0; t < 4; ++t) {
        xs[t]  = (float)(wv * 64 + t * 16 + (lane & 15));
        xxs[t] = xs[t] * xs[t];
    }

    for (int base = 0; base < N; base += CHUNKG) {
        __syncthreads();   // previous pass done reading prm/bfr/scnt

        // ---- Phase 1a: project + cull flag ----
        float A = 0.f, Bc = 0.f, E = -INFINITY;
        float4 cf = make_float4(0.f, 0.f, 0.f, 0.f);
        float rowpeak = -INFINITY;
        {
            const int n = base + tid;
            if (n < N) {
                const float wx = means[3 * n + 0];
                const float wy = means[3 * n + 1];
                const float wz = means[3 * n + 2];
                const float px = M[0] * wx + M[1] * wy + M[2]  * wz + M[3];
                const float py = M[4] * wx + M[5] * wy + M[6]  * wz + M[7];
                const float pz = M[8] * wx + M[9] * wy + M[10] * wz + M[11];
                const float rz = 1.0f / pz;
                const float u  = (K[0] * px + K[1] * py + K[2] * pz) * rz;
                const float v  = (K[4] * py + K[5] * pz) * rz;
                const bool valid = (pz > 1e-4f)
                                && (u >= -(float)WW) && (u <= 2.0f * (float)WW)
                                && (v >= -(float)HH) && (v <= 2.0f * (float)HH);
                if (valid) {
                    const float op  = opacity[n];
                    const float sig = fmaxf(scales[n] * 256.0f, 1.0f);
                    const float coef = -0.72134752044448170368f / (sig * sig);
                    const float lop = __log2f(op);              // op=0 -> -inf
                    const float dyv = yf - v;
                    rowpeak = fmaf(coef, dyv * dyv, lop);       // true row max
                    A  = coef;
                    Bc = -2.0f * coef * u;
                    const float C = -2.0f * coef * v;
                    const float D = fmaf(coef, fmaf(u, u, v * v), lop);
                    E  = fmaf(fmaf(A, yf, C), yf, D);
                    cf = make_float4(colors[3 * n + 0], colors[3 * n + 1],
                                     colors[3 * n + 2], pz);
                }
            }
        }
        const bool keep = (rowpeak > ECUT);
        const unsigned long long mask = __ballot(keep);
        const int prefix = __popcll(mask & ((1ull << lane) - 1ull));
        if (lane == 0) scnt[wv] = __popcll(mask);
        __syncthreads();

        int basepos = 0;
        #pragma unroll
        for (int w = 0; w < 4; ++w) if (w < wv) basepos += scnt[w];
        const int cnt    = scnt[0] + scnt[1] + scnt[2] + scnt[3];
        const int padded = (cnt + 31) & ~31;
        const int nch    = padded >> 5;

        // ---- Phase 1b: compacted writes + pad dummies ----
        if (keep) {
            const int pos = basepos + prefix;
            prm[PADIDX(pos)] = make_float4(A, Bc, E, 0.f);
            colf[pos] = cf;
        }
        if (tid < padded - cnt) {
            const int pos = cnt + tid;
            prm[PADIDX(pos)] = make_float4(0.f, 0.f, -INFINITY, 0.f);
            colf[pos] = make_float4(0.f, 0.f, 0.f, 0.f);
        }
        __syncthreads();

        // ---- Phase 2: build B-fragments ----
        for (int e = tid; e < nch * 256; e += NTHREADS) {
            const int lane6 = (e >> 2) & 63;
            const int reg   = e & 3;
            const int kl    = ((e >> 8) << 5) + ((lane6 >> 4) << 3) + (reg << 1);
            const int col   = lane6 & 15;
            const float4 c0 = colf[kl];
            const float4 c1 = colf[kl + 1];
            const float lo = (col == 0) ? 1.f : (col == 1) ? c0.x : (col == 2) ? c0.y
                           : (col == 3) ? c0.z : (col == 4) ? c0.w : 0.f;
            const float hi = (col == 0) ? 1.f : (col == 1) ? c1.x : (col == 2) ? c1.y
                           : (col == 3) ? c1.z : (col == 4) ? c1.w : 0.f;
            bfr[e] = pk_trunc(lo, hi);
        }
        __syncthreads();

        // ---- Phase 3: alpha eval + MFMA accumulate ----
        for (int c = 0; c < nch; ++c) {
            float4 P[8];
            #pragma unroll
            for (int j = 0; j < 8; ++j) P[j] = prm[PADIDX(c * 32 + kq) + j];

            union { s8v v; uint4 q; } Bf;
            Bf.q = *(const uint4*)&bfr[c * 256 + lane * 4];

            #pragma unroll
            for (int t = 0; t < 4; ++t) {
                union { s8v v; unsigned u[4]; } Af;
                #pragma unroll
                for (int r = 0; r < 4; ++r) {
                    const float4 p0 = P[2 * r];
                    const float4 p1 = P[2 * r + 1];
                    const float a0 = fminf(fexp2(fmaf(p0.y, xs[t], fmaf(p0.x, xxs[t], p0.z))), 0.95f);
                    const float a1 = fminf(fexp2(fmaf(p1.y, xs[t], fmaf(p1.x, xxs[t], p1.z))), 0.95f);
                    Af.u[r] = pk_trunc(a0, a1);
                }
                acc[t] = __builtin_amdgcn_mfma_f32_16x16x32_bf16(Af.v, Bf.v, acc[t], 0, 0, 0);
            }
        }
    }

    // ---- Epilogue: transpose acc through LDS, normalize, store ----
    __syncthreads();
    const int col = lane & 15;
    if (col < 5) {
        const int rb = (lane >> 4) << 2;
        #pragma unroll
        for (int t = 0; t < 4; ++t) {
            #pragma unroll
            for (int r = 0; r < 4; ++r) {
                esum[col * 256 + wv * 64 + t * 16 + rb + r] = acc[t][r];
            }
        }
    }
    __syncthreads();

    const float s  = esum[0 * 256 + tid];
    const float ar = esum[1 * 256 + tid];
    const float ag = esum[2 * 256 + tid];
    const float ab = esum[3 * 256 + tid];
    const float az = esum[4 * 256 + tid];
    const float inv   = 1.0f / (s + 1e-6f);
    const float accum = fminf(s, 1.0f);
    const float bg    = 1.0f - accum;
    float* o = out + (size_t)y * WW + tid;
    o[0 * HWPIX] = fminf(fmaxf(fmaf(ar * inv, accum, bg), 0.0f), 1.0f);
    o[1 * HWPIX] = fminf(fmaxf(fmaf(ag * inv, accum, bg), 0.0f), 1.0f);
    o[2 * HWPIX] = fminf(fmaxf(fmaf(ab * inv, accum, bg), 0.0f), 1.0f);
    o[3 * HWPIX] = accum;
    o[4 * HWPIX] = az * inv;
}

extern "C" void kernel_launch(void* const* d_in, const int* in_sizes, int n_in,
                              void* d_out, int out_size, void* d_ws, size_t ws_size,
                              hipStream_t stream) {
    const float* means      = (const float*)d_in[0];
    const float* colors     = (const float*)d_in[1];
    const float* opacity    = (const float*)d_in[2];
    const float* scales     = (const float*)d_in[3];
    const float* intrinsics = (const float*)d_in[4];
    const float* w2c        = (const float*)d_in[5];
    float* out = (float*)d_out;

    const int N = in_sizes[0] / 3;

    render_kernel<<<HH, NTHREADS, 0, stream>>>(
        means, colors, opacity, scales, intrinsics, w2c, out, N);
}

// Round 13
// 16.056 us; speedup vs baseline: 7.2599x; 1.2076x over previous
//
#include <hip/hip_runtime.h>
#include <math.h>

#define HH 256
#define WW 256
#define NTHREADS 256
#define CHUNKG 256            // gaussians projected per staging pass
#define BPX 128               // pixels (columns) per block
#define HWPIX (HH * WW)
#define PADIDX(i) ((i) + ((i) >> 3))   // quadrant reads hit distinct banks
#define ECUT (-15.0f)                  // drop gaussians whose BLOCK-peak log2(alpha) < ECUT

typedef short s8v __attribute__((ext_vector_type(8)));   // 8 bf16 (4 VGPRs)
typedef float f4v __attribute__((ext_vector_type(4)));   // MFMA accumulator

__device__ __forceinline__ unsigned pk_trunc(float lo, float hi) {
    return (__float_as_uint(hi) & 0xFFFF0000u) | (__float_as_uint(lo) >> 16);
}
__device__ __forceinline__ float fexp2(float x) {
    return __builtin_amdgcn_exp2f(x);   // raw v_exp_f32; -inf -> 0
}

// ---------------------------------------------------------------------------
// Single-kernel renderer, col-split. Block = (row y, x-half) from
// blockIdx.x = y*2 + xhalf; grid = 512 -> 2 blocks/CU (8 waves/CU) so
// independent barrier-groups overlap each other's phases.
// Cull on the BLOCK-Range peak (exact max of log2(alpha) over this block's
// 128 pixels): peak = coef*((y-v)^2 + dxc^2) + log2(op),
// dxc = clamp(u, x0, x0+127) - u. Survivors ballot-compacted, padded to x32
// with E=-inf dummies (exp2 -> exact 0).
//   log2(alpha) = A*x^2 + B*x + E,  E = (A*y + C)*y + D
// GEMM via mfma_f32_16x16x32_bf16 (A=alpha 16px x 32g, B=payload {1,r,g,b,z});
// k=(lane>>4)*8+j enumeration both sides; D: col=lane&15, row=(lane>>4)*4+reg.
// Each of 4 waves owns 32 px (2 tiles). Epilogue: LDS transpose -> 128 px out.
// ---------------------------------------------------------------------------
__global__ __launch_bounds__(NTHREADS) void render_kernel(
    const float* __restrict__ means,
    const float* __restrict__ colors,
    const float* __restrict__ opacity,
    const float* __restrict__ scales,
    const float* __restrict__ K,
    const float* __restrict__ M,
    float* __restrict__ out,
    int N)
{
    __shared__ float4   prm[PADIDX(CHUNKG - 1) + 1];   // {A, B, E, 0}
    __shared__ float4   colf[CHUNKG];                  // {r, g, b, z}
    __shared__ unsigned bfr[(CHUNKG / 32) * 256];      // B-frags (8KB max)
    __shared__ int      scnt[4];
    __shared__ float    esum[5 * BPX];                 // epilogue transpose

    const int tid  = threadIdx.x;
    const int lane = tid & 63;
    const int wv   = tid >> 6;
    const int y    = blockIdx.x >> 1;
    const int x0   = (blockIdx.x & 1) * BPX;
    const float yf  = (float)y;
    const float x0f = (float)x0;
    const int kq   = (lane >> 4) << 3;   // lane's k-block base (0,8,16,24)

    f4v acc[2];
    acc[0] = (f4v){0.f, 0.f, 0.f, 0.f};
    acc[1] = (f4v){0.f, 0.f, 0.f, 0.f};

    float xs[2], xxs[2];
    #pragma unroll
    for (int t = 0; t < 2; ++t) {
        xs[t]  = (float)(x0 + wv * 32 + t * 16 + (lane & 15));
        xxs[t] = xs[t] * xs[t];
    }

    for (int base = 0; base < N; base += CHUNKG) {
        __syncthreads();   // previous pass done reading prm/bfr/scnt

        // ---- Phase 1a: project + block-range cull flag ----
        float A = 0.f, Bc = 0.f, E = -INFINITY;
        float4 cf = make_float4(0.f, 0.f, 0.f, 0.f);
        float blkpeak = -INFINITY;
        {
            const int n = base + tid;
            if (n < N) {
                const float wx = means[3 * n + 0];
                const float wy = means[3 * n + 1];
                const float wz = means[3 * n + 2];
                const float px = M[0] * wx + M[1] * wy + M[2]  * wz + M[3];
                const float py = M[4] * wx + M[5] * wy + M[6]  * wz + M[7];
                const float pz = M[8] * wx + M[9] * wy + M[10] * wz + M[11];
                const float rz = 1.0f / pz;
                const float u  = (K[0] * px + K[1] * py + K[2] * pz) * rz;
                const float v  = (K[4] * py + K[5] * pz) * rz;
                const bool valid = (pz > 1e-4f)
                                && (u >= -(float)WW) && (u <= 2.0f * (float)WW)
                                && (v >= -(float)HH) && (v <= 2.0f * (float)HH);
                if (valid) {
                    const float op  = opacity[n];
                    const float sig = fmaxf(scales[n] * 256.0f, 1.0f);
                    const float coef = -0.72134752044448170368f / (sig * sig);
                    const float lop = __log2f(op);              // op=0 -> -inf
                    const float dyv = yf - v;
                    const float xc  = fminf(fmaxf(u, x0f), x0f + (float)(BPX - 1));
                    const float dxc = xc - u;
                    blkpeak = fmaf(coef, fmaf(dxc, dxc, dyv * dyv), lop);
                    A  = coef;
                    Bc = -2.0f * coef * u;
                    const float C = -2.0f * coef * v;
                    const float D = fmaf(coef, fmaf(u, u, v * v), lop);
                    E  = fmaf(fmaf(A, yf, C), yf, D);
                    cf = make_float4(colors[3 * n + 0], colors[3 * n + 1],
                                     colors[3 * n + 2], pz);
                }
            }
        }
        const bool keep = (blkpeak > ECUT);
        const unsigned long long mask = __ballot(keep);
        const int prefix = __popcll(mask & ((1ull << lane) - 1ull));
        if (lane == 0) scnt[wv] = __popcll(mask);
        __syncthreads();

        int basepos = 0;
        #pragma unroll
        for (int w = 0; w < 4; ++w) if (w < wv) basepos += scnt[w];
        const int cnt    = scnt[0] + scnt[1] + scnt[2] + scnt[3];
        const int padded = (cnt + 31) & ~31;
        const int nch    = padded >> 5;

        // ---- Phase 1b: compacted writes + pad dummies ----
        if (keep) {
            const int pos = basepos + prefix;
            prm[PADIDX(pos)] = make_float4(A, Bc, E, 0.f);
            colf[pos] = cf;
        }
        if (tid < padded - cnt) {
            const int pos = cnt + tid;
            prm[PADIDX(pos)] = make_float4(0.f, 0.f, -INFINITY, 0.f);
            colf[pos] = make_float4(0.f, 0.f, 0.f, 0.f);
        }
        __syncthreads();

        // ---- Phase 2: build B-fragments ----
        for (int e = tid; e < nch * 256; e += NTHREADS) {
            const int lane6 = (e >> 2) & 63;
            const int reg   = e & 3;
            const int kl    = ((e >> 8) << 5) + ((lane6 >> 4) << 3) + (reg << 1);
            const int col   = lane6 & 15;
            const float4 c0 = colf[kl];
            const float4 c1 = colf[kl + 1];
            const float lo = (col == 0) ? 1.f : (col == 1) ? c0.x : (col == 2) ? c0.y
                           : (col == 3) ? c0.z : (col == 4) ? c0.w : 0.f;
            const float hi = (col == 0) ? 1.f : (col == 1) ? c1.x : (col == 2) ? c1.y
                           : (col == 3) ? c1.z : (col == 4) ? c1.w : 0.f;
            bfr[e] = pk_trunc(lo, hi);
        }
        __syncthreads();

        // ---- Phase 3: alpha eval + MFMA accumulate ----
        for (int c = 0; c < nch; ++c) {
            float4 P[8];
            #pragma unroll
            for (int j = 0; j < 8; ++j) P[j] = prm[PADIDX(c * 32 + kq) + j];

            union { s8v v; uint4 q; } Bf;
            Bf.q = *(const uint4*)&bfr[c * 256 + lane * 4];

            #pragma unroll
            for (int t = 0; t < 2; ++t) {
                union { s8v v; unsigned u[4]; } Af;
                #pragma unroll
                for (int r = 0; r < 4; ++r) {
                    const float4 p0 = P[2 * r];
                    const float4 p1 = P[2 * r + 1];
                    const float a0 = fminf(fexp2(fmaf(p0.y, xs[t], fmaf(p0.x, xxs[t], p0.z))), 0.95f);
                    const float a1 = fminf(fexp2(fmaf(p1.y, xs[t], fmaf(p1.x, xxs[t], p1.z))), 0.95f);
                    Af.u[r] = pk_trunc(a0, a1);
                }
                acc[t] = __builtin_amdgcn_mfma_f32_16x16x32_bf16(Af.v, Bf.v, acc[t], 0, 0, 0);
            }
        }
    }

    // ---- Epilogue: transpose acc through LDS, normalize, store ----
    __syncthreads();
    const int col = lane & 15;
    if (col < 5) {
        const int rb = (lane >> 4) << 2;
        #pragma unroll
        for (int t = 0; t < 2; ++t) {
            #pragma unroll
            for (int r = 0; r < 4; ++r) {
                esum[col * BPX + wv * 32 + t * 16 + rb + r] = acc[t][r];
            }
        }
    }
    __syncthreads();

    if (tid < BPX) {
        const float s  = esum[0 * BPX + tid];
        const float ar = esum[1 * BPX + tid];
        const float ag = esum[2 * BPX + tid];
        const float ab = esum[3 * BPX + tid];
        const float az = esum[4 * BPX + tid];
        const float inv   = 1.0f / (s + 1e-6f);
        const float accum = fminf(s, 1.0f);
        const float bg    = 1.0f - accum;
        float* o = out + (size_t)y * WW + x0 + tid;
        o[0 * HWPIX] = fminf(fmaxf(fmaf(ar * inv, accum, bg), 0.0f), 1.0f);
        o[1 * HWPIX] = fminf(fmaxf(fmaf(ag * inv, accum, bg), 0.0f), 1.0f);
        o[2 * HWPIX] = fminf(fmaxf(fmaf(ab * inv, accum, bg), 0.0f), 1.0f);
        o[3 * HWPIX] = accum;
        o[4 * HWPIX] = az * inv;
    }
}

extern "C" void kernel_launch(void* const* d_in, const int* in_sizes, int n_in,
                              void* d_out, int out_size, void* d_ws, size_t ws_size,
                              hipStream_t stream) {
    const float* means      = (const float*)d_in[0];
    const float* colors     = (const float*)d_in[1];
    const float* opacity    = (const float*)d_in[2];
    const float* scales     = (const float*)d_in[3];
    const float* intrinsics = (const float*)d_in[4];
    const float* w2c        = (const float*)d_in[5];
    float* out = (float*)d_out;

    const int N = in_sizes[0] / 3;

    render_kernel<<<HH * 2, NTHREADS, 0, stream>>>(
        means, colors, opacity, scales, intrinsics, w2c, out, N);
}

// Round 14
// 14.302 us; speedup vs baseline: 8.1501x; 1.1226x over previous
//
#include <hip/hip_runtime.h>
#include <math.h>

#define HH 256
#define WW 256
#define NTHREADS 256
#define CHUNKG 512            // gaussians projected per staging pass (2 rounds of 256)
#define BPX 128               // pixels (columns) per block
#define HWPIX (HH * WW)
#define ECUT (-15.0f)         // drop gaussians whose BLOCK-peak log2(alpha) < ECUT

typedef short s8v __attribute__((ext_vector_type(8)));   // 8 bf16 (4 VGPRs)
typedef float f4v __attribute__((ext_vector_type(4)));   // MFMA accumulator

__device__ __forceinline__ unsigned pk_trunc(float lo, float hi) {
    return (__float_as_uint(hi) & 0xFFFF0000u) | (__float_as_uint(lo) >> 16);
}
__device__ __forceinline__ float fexp2(float x) {
    return __builtin_amdgcn_exp2f(x);   // raw v_exp_f32; -inf -> 0
}

// ---------------------------------------------------------------------------
// Single-kernel renderer. Block = (row y, x-half); grid = 512 (2 blocks/CU).
// 2 staging passes of 512 gaussians (2 projection rounds each, register-held),
// ballot-compacted on the BLOCK-range peak (exact max of log2(alpha) over the
// block's 128 px): peak = coef*((y-v)^2 + dxc^2) + log2(op),
// dxc = clamp(u,x0,x0+127)-u. Survivors padded to x32 with E=-inf dummies.
//   log2(alpha) = A*x^2 + B*x + E,  E = (A*y + C)*y + D
// prm packed 3-float {A,B,E}: a quadrant's 8 gaussians = 6 ds_read_b128
// (bases 96B apart -> banks {0,24,16,8}: conflict-free). GEMM via
// mfma_f32_16x16x32_bf16 (A=alpha 16px x 32g, B=payload {1,r,g,b,z});
// k=(lane>>4)*8+j both sides; D: col=lane&15, row=(lane>>4)*4+reg.
// Epilogue: LDS transpose -> normalize -> 128 px out. No ws, no fences.
// ---------------------------------------------------------------------------
__global__ __launch_bounds__(NTHREADS) void render_kernel(
    const float* __restrict__ means,
    const float* __restrict__ colors,
    const float* __restrict__ opacity,
    const float* __restrict__ scales,
    const float* __restrict__ K,
    const float* __restrict__ M,
    float* __restrict__ out,
    int N)
{
    __shared__ float    prm3[CHUNKG * 3];              // packed {A,B,E}
    __shared__ float4   colf[CHUNKG];                  // {r, g, b, z}
    __shared__ unsigned bfr[(CHUNKG / 32) * 256];      // B-frags (16KB max)
    __shared__ int      scnt[8];                       // per-round x per-wave counts
    __shared__ float    esum[5 * BPX];                 // epilogue transpose

    const int tid  = threadIdx.x;
    const int lane = tid & 63;
    const int wv   = tid >> 6;
    const int y    = blockIdx.x >> 1;
    const int x0   = (blockIdx.x & 1) * BPX;
    const float yf  = (float)y;
    const float x0f = (float)x0;
    const int kq   = (lane >> 4) << 3;   // lane's k-block base (0,8,16,24)

    f4v acc[2];
    acc[0] = (f4v){0.f, 0.f, 0.f, 0.f};
    acc[1] = (f4v){0.f, 0.f, 0.f, 0.f};

    float xs[2], xxs[2];
    #pragma unroll
    for (int t = 0; t < 2; ++t) {
        xs[t]  = (float)(x0 + wv * 32 + t * 16 + (lane & 15));
        xxs[t] = xs[t] * xs[t];
    }

    for (int base = 0; base < N; base += CHUNKG) {
        __syncthreads();   // all waves done reading prm3/bfr/scnt of prev pass

        // ---- Phase 1: project 2 rounds into registers + ballot counts ----
        float A0 = 0.f, B0 = 0.f, E0 = -INFINITY;
        float A1 = 0.f, B1 = 0.f, E1 = -INFINITY;
        float4 cf0 = make_float4(0.f, 0.f, 0.f, 0.f);
        float4 cf1 = make_float4(0.f, 0.f, 0.f, 0.f);
        bool keep0 = false, keep1 = false;
        int pre0 = 0, pre1 = 0;

        #pragma unroll
        for (int r = 0; r < 2; ++r) {
            const int n = base + r * NTHREADS + tid;
            float A = 0.f, Bc = 0.f, E = -INFINITY;
            float4 cf = make_float4(0.f, 0.f, 0.f, 0.f);
            float blkpeak = -INFINITY;
            if (n < N) {
                const float wx = means[3 * n + 0];
                const float wy = means[3 * n + 1];
                const float wz = means[3 * n + 2];
                const float px = M[0] * wx + M[1] * wy + M[2]  * wz + M[3];
                const float py = M[4] * wx + M[5] * wy + M[6]  * wz + M[7];
                const float pz = M[8] * wx + M[9] * wy + M[10] * wz + M[11];
                const float rz = 1.0f / pz;
                const float u  = (K[0] * px + K[1] * py + K[2] * pz) * rz;
                const float v  = (K[4] * py + K[5] * pz) * rz;
                const bool valid = (pz > 1e-4f)
                                && (u >= -(float)WW) && (u <= 2.0f * (float)WW)
                                && (v >= -(float)HH) && (v <= 2.0f * (float)HH);
                if (valid) {
                    const float op  = opacity[n];
                    const float sig = fmaxf(scales[n] * 256.0f, 1.0f);
                    const float coef = -0.72134752044448170368f / (sig * sig);
                    const float lop = __log2f(op);              // op=0 -> -inf
                    const float dyv = yf - v;
                    const float xc  = fminf(fmaxf(u, x0f), x0f + (float)(BPX - 1));
                    const float dxc = xc - u;
                    blkpeak = fmaf(coef, fmaf(dxc, dxc, dyv * dyv), lop);
                    A  = coef;
                    Bc = -2.0f * coef * u;
                    const float C = -2.0f * coef * v;
                    const float D = fmaf(coef, fmaf(u, u, v * v), lop);
                    E  = fmaf(fmaf(A, yf, C), yf, D);
                    cf = make_float4(colors[3 * n + 0], colors[3 * n + 1],
                                     colors[3 * n + 2], pz);
                }
            }
            const bool keep = (blkpeak > ECUT);
            const unsigned long long mask = __ballot(keep);
            const int prefix = __popcll(mask & ((1ull << lane) - 1ull));
            if (lane == 0) scnt[r * 4 + wv] = __popcll(mask);
            if (r == 0) { A0 = A; B0 = Bc; E0 = E; cf0 = cf; keep0 = keep; pre0 = prefix; }
            else        { A1 = A; B1 = Bc; E1 = E; cf1 = cf; keep1 = keep; pre1 = prefix; }
        }
        __syncthreads();

        int base0 = 0, base1 = 0, cnt = 0;
        #pragma unroll
        for (int w = 0; w < 4; ++w) {
            if (w < wv) base0 += scnt[w];
            base1 += scnt[w];                       // all of round 0
            if (w < wv) base1 += scnt[4 + w];
            cnt += scnt[w] + scnt[4 + w];
        }
        const int padded = (cnt + 31) & ~31;
        const int nch    = padded >> 5;

        // ---- Phase 1b: compacted writes + pad dummies ----
        if (keep0) {
            const int pos = base0 + pre0;
            prm3[3 * pos + 0] = A0;
            prm3[3 * pos + 1] = B0;
            prm3[3 * pos + 2] = E0;
            colf[pos] = cf0;
        }
        if (keep1) {
            const int pos = base1 + pre1;
            prm3[3 * pos + 0] = A1;
            prm3[3 * pos + 1] = B1;
            prm3[3 * pos + 2] = E1;
            colf[pos] = cf1;
        }
        if (tid < padded - cnt) {
            const int pos = cnt + tid;
            prm3[3 * pos + 0] = 0.f;
            prm3[3 * pos + 1] = 0.f;
            prm3[3 * pos + 2] = -INFINITY;
            colf[pos] = make_float4(0.f, 0.f, 0.f, 0.f);
        }
        __syncthreads();

        // ---- Phase 2: build B-fragments ----
        for (int e = tid; e < nch * 256; e += NTHREADS) {
            const int lane6 = (e >> 2) & 63;
            const int reg   = e & 3;
            const int kl    = ((e >> 8) << 5) + ((lane6 >> 4) << 3) + (reg << 1);
            const int col   = lane6 & 15;
            const float4 c0 = colf[kl];
            const float4 c1 = colf[kl + 1];
            const float lo = (col == 0) ? 1.f : (col == 1) ? c0.x : (col == 2) ? c0.y
                           : (col == 3) ? c0.z : (col == 4) ? c0.w : 0.f;
            const float hi = (col == 0) ? 1.f : (col == 1) ? c1.x : (col == 2) ? c1.y
                           : (col == 3) ? c1.z : (col == 4) ? c1.w : 0.f;
            bfr[e] = pk_trunc(lo, hi);
        }
        __syncthreads();

        // ---- Phase 3: alpha eval + MFMA accumulate ----
        const float4* prm4 = (const float4*)prm3;
        for (int c = 0; c < nch; ++c) {
            // quadrant base in float4 units: ((c*32 + kq)*3)/4 = 24c + 6*(kq>>3)
            const int qb = 24 * c + 6 * (kq >> 3);
            float4 q0 = prm4[qb + 0], q1 = prm4[qb + 1], q2 = prm4[qb + 2];
            float4 q3 = prm4[qb + 3], q4 = prm4[qb + 4], q5 = prm4[qb + 5];
            // unpack 8 gaussians {A,B,E}
            const float Ag[8] = {q0.x, q0.w, q1.z, q2.y, q3.x, q3.w, q4.z, q5.y};
            const float Bg[8] = {q0.y, q1.x, q1.w, q2.z, q3.y, q4.x, q4.w, q5.z};
            const float Eg[8] = {q0.z, q1.y, q2.x, q2.w, q3.z, q4.y, q5.x, q5.w};

            union { s8v v; uint4 q; } Bf;
            Bf.q = *(const uint4*)&bfr[c * 256 + lane * 4];

            #pragma unroll
            for (int t = 0; t < 2; ++t) {
                union { s8v v; unsigned u[4]; } Af;
                #pragma unroll
                for (int r = 0; r < 4; ++r) {
                    const float a0 = fminf(fexp2(fmaf(Bg[2*r],   xs[t], fmaf(Ag[2*r],   xxs[t], Eg[2*r]))),   0.95f);
                    const float a1 = fminf(fexp2(fmaf(Bg[2*r+1], xs[t], fmaf(Ag[2*r+1], xxs[t], Eg[2*r+1]))), 0.95f);
                    Af.u[r] = pk_trunc(a0, a1);
                }
                acc[t] = __builtin_amdgcn_mfma_f32_16x16x32_bf16(Af.v, Bf.v, acc[t], 0, 0, 0);
            }
        }
    }

    // ---- Epilogue: transpose acc through LDS, normalize, store ----
    __syncthreads();
    const int col = lane & 15;
    if (col < 5) {
        const int rb = (lane >> 4) << 2;
        #pragma unroll
        for (int t = 0; t < 2; ++t) {
            #pragma unroll
            for (int r = 0; r < 4; ++r) {
                esum[col * BPX + wv * 32 + t * 16 + rb + r] = acc[t][r];
            }
        }
    }
    __syncthreads();

    if (tid < BPX) {
        const float s  = esum[0 * BPX + tid];
        const float ar = esum[1 * BPX + tid];
        const float ag = esum[2 * BPX + tid];
        const float ab = esum[3 * BPX + tid];
        const float az = esum[4 * BPX + tid];
        const float inv   = 1.0f / (s + 1e-6f);
        const float accum = fminf(s, 1.0f);
        const float bg    = 1.0f - accum;
        float* o = out + (size_t)y * WW + x0 + tid;
        o[0 * HWPIX] = fminf(fmaxf(fmaf(ar * inv, accum, bg), 0.0f), 1.0f);
        o[1 * HWPIX] = fminf(fmaxf(fmaf(ag * inv, accum, bg), 0.0f), 1.0f);
        o[2 * HWPIX] = fminf(fmaxf(fmaf(ab * inv, accum, bg), 0.0f), 1.0f);
        o[3 * HWPIX] = accum;
        o[4 * HWPIX] = az * inv;
    }
}

extern "C" void kernel_launch(void* const* d_in, const int* in_sizes, int n_in,
                              void* d_out, int out_size, void* d_ws, size_t ws_size,
                              hipStream_t stream) {
    const float* means      = (const float*)d_in[0];
    const float* colors     = (const float*)d_in[1];
    const float* opacity    = (const float*)d_in[2];
    const float* scales     = (const float*)d_in[3];
    const float* intrinsics = (const float*)d_in[4];
    const float* w2c        = (const float*)d_in[5];
    float* out = (float*)d_out;

    const int N = in_sizes[0] / 3;

    render_kernel<<<HH * 2, NTHREADS, 0, stream>>>(
        means, colors, opacity, scales, intrinsics, w2c, out, N);
}

// Round 15
// 12.566 us; speedup vs baseline: 9.2763x; 1.1382x over previous
//
#include <hip/hip_runtime.h>
#include <math.h>

#define HH 256
#define WW 256
#define NTHREADS 256
#define CHUNKG 1024           // gaussians per staging pass (N fits in one pass)
#define NROUND (CHUNKG / NTHREADS)
#define BPX 128               // pixels (columns) per block
#define HWPIX (HH * WW)
#define ECUT (-15.0f)         // drop gaussians whose BLOCK-peak log2(alpha) < ECUT

typedef short s8v __attribute__((ext_vector_type(8)));   // 8 bf16 (4 VGPRs)
typedef float f4v __attribute__((ext_vector_type(4)));   // MFMA accumulator

__device__ __forceinline__ unsigned pk_trunc(float lo, float hi) {
    return (__float_as_uint(hi) & 0xFFFF0000u) | (__float_as_uint(lo) >> 16);
}
__device__ __forceinline__ short bf16h(float v) {
    return (short)(__float_as_uint(v) >> 16);
}
__device__ __forceinline__ float fexp2(float x) {
    return __builtin_amdgcn_exp2f(x);   // raw v_exp_f32; -inf -> 0
}

// ---------------------------------------------------------------------------
// Single-kernel, single-pass renderer. Block = (row y, x-half); grid = 512
// (2 blocks/CU). All N gaussians staged in ONE pass: 4 projection rounds held
// in registers -> one ballot-compact -> direct scatter into LDS:
//   prm3[pos] = {A,B,E}   (packed 3-float; quadrant = 6 conflict-free b128)
//   bfr payload written DIRECTLY as ds_write_b16 into MFMA B-frag slots
//     entry = chunk*256 + (kblock*16+col)*4 + reg, half = j&1
//   (bfr zero-filled once at start: dummy k-slots and cols 5..15 stay finite
//    0 so alpha=0 x B=0 contributes exact 0; stale finite bf16 on later
//    passes is equally harmless)
// Cull: block-range peak coef*((y-v)^2 + dxc^2) + log2(op) > ECUT,
// dxc = clamp(u,x0,x0+127)-u. log2(alpha) = A*x^2 + B*x + E.
// GEMM mfma_f32_16x16x32_bf16, k=(lane>>4)*8+j both sides;
// D: col=lane&15, row=(lane>>4)*4+reg. Epilogue: LDS transpose -> out.
// ---------------------------------------------------------------------------
__global__ __launch_bounds__(NTHREADS) void render_kernel(
    const float* __restrict__ means,
    const float* __restrict__ colors,
    const float* __restrict__ opacity,
    const float* __restrict__ scales,
    const float* __restrict__ K,
    const float* __restrict__ M,
    float* __restrict__ out,
    int N)
{
    __shared__ float    prm3[CHUNKG * 3];              // packed {A,B,E}
    __shared__ unsigned bfr[(CHUNKG / 32) * 256];      // B-frags (32KB)
    __shared__ int      scnt[4 * NROUND];
    __shared__ float    esum[5 * BPX];

    short* bfr16 = (short*)bfr;

    const int tid  = threadIdx.x;
    const int lane = tid & 63;
    const int wv   = tid >> 6;
    const int y    = blockIdx.x >> 1;
    const int x0   = (blockIdx.x & 1) * BPX;
    const float yf  = (float)y;
    const float x0f = (float)x0;
    const int kq   = (lane >> 4) << 3;   // lane's k-block base (0,8,16,24)

    // one-time zero of all B-frag slots (protected by loop-top barrier)
    for (int e = tid; e < (CHUNKG / 32) * 256; e += NTHREADS) bfr[e] = 0;

    f4v acc[2];
    acc[0] = (f4v){0.f, 0.f, 0.f, 0.f};
    acc[1] = (f4v){0.f, 0.f, 0.f, 0.f};

    float xs[2], xxs[2];
    #pragma unroll
    for (int t = 0; t < 2; ++t) {
        xs[t]  = (float)(x0 + wv * 32 + t * 16 + (lane & 15));
        xxs[t] = xs[t] * xs[t];
    }

    for (int base = 0; base < N; base += CHUNKG) {
        __syncthreads();   // zero-fill done / previous pass fully consumed

        // ---- Phase 1: project NROUND rounds into registers + ballots ----
        float Ar[NROUND], Br[NROUND], Er[NROUND];
        float4 cfr[NROUND];
        bool  keepr[NROUND];
        int   prer[NROUND];

        #pragma unroll
        for (int r = 0; r < NROUND; ++r) {
            const int n = base + r * NTHREADS + tid;
            float A = 0.f, Bc = 0.f, E = -INFINITY;
            float4 cf = make_float4(0.f, 0.f, 0.f, 0.f);
            float blkpeak = -INFINITY;
            if (n < N) {
                const float wx = means[3 * n + 0];
                const float wy = means[3 * n + 1];
                const float wz = means[3 * n + 2];
                const float px = M[0] * wx + M[1] * wy + M[2]  * wz + M[3];
                const float py = M[4] * wx + M[5] * wy + M[6]  * wz + M[7];
                const float pz = M[8] * wx + M[9] * wy + M[10] * wz + M[11];
                const float rz = 1.0f / pz;
                const float u  = (K[0] * px + K[1] * py + K[2] * pz) * rz;
                const float v  = (K[4] * py + K[5] * pz) * rz;
                const bool valid = (pz > 1e-4f)
                                && (u >= -(float)WW) && (u <= 2.0f * (float)WW)
                                && (v >= -(float)HH) && (v <= 2.0f * (float)HH);
                if (valid) {
                    const float op  = opacity[n];
                    const float sig = fmaxf(scales[n] * 256.0f, 1.0f);
                    const float coef = -0.72134752044448170368f / (sig * sig);
                    const float lop = __log2f(op);              // op=0 -> -inf
                    const float dyv = yf - v;
                    const float xc  = fminf(fmaxf(u, x0f), x0f + (float)(BPX - 1));
                    const float dxc = xc - u;
                    blkpeak = fmaf(coef, fmaf(dxc, dxc, dyv * dyv), lop);
                    A  = coef;
                    Bc = -2.0f * coef * u;
                    const float C = -2.0f * coef * v;
                    const float D = fmaf(coef, fmaf(u, u, v * v), lop);
                    E  = fmaf(fmaf(A, yf, C), yf, D);
                    cf = make_float4(colors[3 * n + 0], colors[3 * n + 1],
                                     colors[3 * n + 2], pz);
                }
            }
            const bool keep = (blkpeak > ECUT);
            const unsigned long long mask = __ballot(keep);
            if (lane == 0) scnt[r * 4 + wv] = __popcll(mask);
            Ar[r] = A; Br[r] = Bc; Er[r] = E; cfr[r] = cf;
            keepr[r] = keep;
            prer[r] = __popcll(mask & ((1ull << lane) - 1ull));
        }
        __syncthreads();

        // position bases (round-major, then wave-major)
        int rbase[NROUND];
        int running = 0;
        #pragma unroll
        for (int r = 0; r < NROUND; ++r) {
            int b = running;
            #pragma unroll
            for (int w = 0; w < 4; ++w) {
                if (w < wv) b += scnt[r * 4 + w];
                running += scnt[r * 4 + w];
            }
            rbase[r] = b;
        }
        const int cnt    = running;
        const int padded = (cnt + 31) & ~31;
        const int nch    = padded >> 5;

        // ---- Phase 2: compacted scatter (prm3 + direct B-frag b16) ----
        #pragma unroll
        for (int r = 0; r < NROUND; ++r) {
            if (keepr[r]) {
                const int pos = rbase[r] + prer[r];
                prm3[3 * pos + 0] = Ar[r];
                prm3[3 * pos + 1] = Br[r];
                prm3[3 * pos + 2] = Er[r];
                const int chunk = pos >> 5;
                const int k     = pos & 31;
                const int eb    = chunk * 256 + (k >> 3) * 64 + ((k & 7) >> 1);
                const int par   = k & 1;
                bfr16[(eb +  0) * 2 + par] = (short)0x3F80;      // col 0: 1.0
                bfr16[(eb +  4) * 2 + par] = bf16h(cfr[r].x);    // col 1: r
                bfr16[(eb +  8) * 2 + par] = bf16h(cfr[r].y);    // col 2: g
                bfr16[(eb + 12) * 2 + par] = bf16h(cfr[r].z);    // col 3: b
                bfr16[(eb + 16) * 2 + par] = bf16h(cfr[r].w);    // col 4: z
            }
        }
        if (tid < padded - cnt) {
            const int pos = cnt + tid;
            prm3[3 * pos + 0] = 0.f;
            prm3[3 * pos + 1] = 0.f;
            prm3[3 * pos + 2] = -INFINITY;
            // bfr slots for dummies remain finite (0 or stale bf16): alpha=0
        }
        __syncthreads();

        // ---- Phase 3: alpha eval + MFMA accumulate ----
        const float4* prm4 = (const float4*)prm3;
        for (int c = 0; c < nch; ++c) {
            const int qb = 24 * c + 6 * (kq >> 3);
            float4 q0 = prm4[qb + 0], q1 = prm4[qb + 1], q2 = prm4[qb + 2];
            float4 q3 = prm4[qb + 3], q4 = prm4[qb + 4], q5 = prm4[qb + 5];
            const float Ag[8] = {q0.x, q0.w, q1.z, q2.y, q3.x, q3.w, q4.z, q5.y};
            const float Bg[8] = {q0.y, q1.x, q1.w, q2.z, q3.y, q4.x, q4.w, q5.z};
            const float Eg[8] = {q0.z, q1.y, q2.x, q2.w, q3.z, q4.y, q5.x, q5.w};

            union { s8v v; uint4 q; } Bf;
            Bf.q = *(const uint4*)&bfr[c * 256 + lane * 4];

            #pragma unroll
            for (int t = 0; t < 2; ++t) {
                union { s8v v; unsigned u[4]; } Af;
                #pragma unroll
                for (int r = 0; r < 4; ++r) {
                    const float a0 = fminf(fexp2(fmaf(Bg[2*r],   xs[t], fmaf(Ag[2*r],   xxs[t], Eg[2*r]))),   0.95f);
                    const float a1 = fminf(fexp2(fmaf(Bg[2*r+1], xs[t], fmaf(Ag[2*r+1], xxs[t], Eg[2*r+1]))), 0.95f);
                    Af.u[r] = pk_trunc(a0, a1);
                }
                acc[t] = __builtin_amdgcn_mfma_f32_16x16x32_bf16(Af.v, Bf.v, acc[t], 0, 0, 0);
            }
        }
    }

    // ---- Epilogue: transpose acc through LDS, normalize, store ----
    __syncthreads();
    const int col = lane & 15;
    if (col < 5) {
        const int rb = (lane >> 4) << 2;
        #pragma unroll
        for (int t = 0; t < 2; ++t) {
            #pragma unroll
            for (int r = 0; r < 4; ++r) {
                esum[col * BPX + wv * 32 + t * 16 + rb + r] = acc[t][r];
            }
        }
    }
    __syncthreads();

    if (tid < BPX) {
        const float s  = esum[0 * BPX + tid];
        const float ar = esum[1 * BPX + tid];
        const float ag = esum[2 * BPX + tid];
        const float ab = esum[3 * BPX + tid];
        const float az = esum[4 * BPX + tid];
        const float inv   = 1.0f / (s + 1e-6f);
        const float accum = fminf(s, 1.0f);
        const float bg    = 1.0f - accum;
        float* o = out + (size_t)y * WW + x0 + tid;
        o[0 * HWPIX] = fminf(fmaxf(fmaf(ar * inv, accum, bg), 0.0f), 1.0f);
        o[1 * HWPIX] = fminf(fmaxf(fmaf(ag * inv, accum, bg), 0.0f), 1.0f);
        o[2 * HWPIX] = fminf(fmaxf(fmaf(ab * inv, accum, bg), 0.0f), 1.0f);
        o[3 * HWPIX] = accum;
        o[4 * HWPIX] = az * inv;
    }
}

extern "C" void kernel_launch(void* const* d_in, const int* in_sizes, int n_in,
                              void* d_out, int out_size, void* d_ws, size_t ws_size,
                              hipStream_t stream) {
    const float* means      = (const float*)d_in[0];
    const float* colors     = (const float*)d_in[1];
    const float* opacity    = (const float*)d_in[2];
    const float* scales     = (const float*)d_in[3];
    const float* intrinsics = (const float*)d_in[4];
    const float* w2c        = (const float*)d_in[5];
    float* out = (float*)d_out;

    const int N = in_sizes[0] / 3;

    render_kernel<<<HH * 2, NTHREADS, 0, stream>>>(
        means, colors, opacity, scales, intrinsics, w2c, out, N);
}